// Round 1
// baseline (1542.088 us; speedup 1.0000x reference)
//
#include <hip/hip_runtime.h>

// Problem constants (match reference)
#define D_   41
#define H_   159
#define W_   159
#define MD   20
#define MH   79
#define MW   79
#define CIN  32
#define COUT 64
#define BATCH 2

// Scatter point index into dense idx grid (-1 = empty).
__global__ void scatter_idx_kernel(const int* __restrict__ coors,
                                   int* __restrict__ idx, int n) {
    int i = blockIdx.x * blockDim.x + threadIdx.x;
    if (i >= n) return;
    int b = coors[i * 4 + 0];
    int z = coors[i * 4 + 1];
    int y = coors[i * 4 + 2];
    int x = coors[i * 4 + 3];
    idx[((b * D_ + z) * H_ + y) * W_ + x] = i;
}

// Compute mid[b,zo,yo,xo,co] densely via gather over 27 taps.
// 256 threads = 4 voxels x 64 lanes (one lane per co).
__global__ void mid_kernel(const float* __restrict__ feat,
                           const int* __restrict__ idx,
                           const float* __restrict__ w1,
                           float* __restrict__ mid) {
    const int NV = BATCH * MD * MH * MW;
    int co = threadIdx.x & 63;
    int v  = blockIdx.x * 4 + (threadIdx.x >> 6);
    if (v >= NV) return;
    int xo = v % MW; int t = v / MW;
    int yo = t % MH; t /= MH;
    int zo = t % MD; int b = t / MD;

    int zi0 = 2 * zo, yi0 = 2 * yo, xi0 = 2 * xo;
    float acc = 0.f;
    // All taps are in-bounds for the VALID strided conv.
    for (int kz = 0; kz < 3; ++kz) {
        for (int ky = 0; ky < 3; ++ky) {
            const int* row = idx + ((b * D_ + zi0 + kz) * H_ + yi0 + ky) * W_ + xi0;
            #pragma unroll
            for (int kx = 0; kx < 3; ++kx) {
                int p = row[kx];                      // wave-uniform broadcast load
                if (p >= 0) {
                    const float* f = feat + (size_t)p * CIN;   // broadcast
                    const float* w = w1 + (((kz * 3 + ky) * 3 + kx) * CIN * COUT) + co;
                    #pragma unroll
                    for (int ci = 0; ci < CIN; ++ci)
                        acc = fmaf(f[ci], w[ci * COUT], acc);  // w reads coalesced in co
                }
            }
        }
    }
    mid[(size_t)v * COUT + co] = acc;
}

// Adjoint conv evaluated ONLY at masked voxels (one lane per (point, ci)).
__global__ void out_kernel(const int* __restrict__ coors,
                           const float* __restrict__ mid,
                           const float* __restrict__ w2,
                           float* __restrict__ out, int n) {
    int tid = blockIdx.x * blockDim.x + threadIdx.x;
    int ci = tid & 31;
    int i  = tid >> 5;
    if (i >= n) return;
    int b = coors[i * 4 + 0];
    int z = coors[i * 4 + 1];
    int y = coors[i * 4 + 2];
    int x = coors[i * 4 + 3];

    float acc = 0.f;
    for (int kz = 0; kz < 3; ++kz) {
        int zr = z - kz;
        if (zr < 0 || (zr & 1)) continue;
        int zo = zr >> 1; if (zo >= MD) continue;
        for (int ky = 0; ky < 3; ++ky) {
            int yr = y - ky;
            if (yr < 0 || (yr & 1)) continue;
            int yo = yr >> 1; if (yo >= MH) continue;
            for (int kx = 0; kx < 3; ++kx) {
                int xr = x - kx;
                if (xr < 0 || (xr & 1)) continue;
                int xo = xr >> 1; if (xo >= MW) continue;
                const float* m = mid + (size_t)(((b * MD + zo) * MH + yo) * MW + xo) * COUT;
                const float* w = w2 + (((kz * 3 + ky) * 3 + kx) * CIN * COUT) + ci * COUT;
                #pragma unroll
                for (int co = 0; co < COUT; ++co)
                    acc = fmaf(m[co], w[co], acc);   // m broadcast across ci lanes
            }
        }
    }
    // out layout: (B, CIN, D, H, W); write only at masked voxel (mask implicit)
    out[((size_t)(b * CIN + ci) * D_ + z) * (H_ * W_) + (size_t)y * W_ + x] = acc;
}

extern "C" void kernel_launch(void* const* d_in, const int* in_sizes, int n_in,
                              void* d_out, int out_size, void* d_ws, size_t ws_size,
                              hipStream_t stream) {
    const float* feat  = (const float*)d_in[0];
    const int*   coors = (const int*)d_in[1];
    // d_in[2] = batch_size (scalar, == BATCH)
    const float* w1    = (const float*)d_in[3];
    const float* w2    = (const float*)d_in[4];
    float*       out   = (float*)d_out;

    int n = in_sizes[0] / CIN;   // 150000 points total

    // Workspace layout: [idx grid int32 (8.3 MB)] [mid f32 (64 MB)]
    int*   idx      = (int*)d_ws;
    size_t idxBytes = (size_t)BATCH * D_ * H_ * W_ * sizeof(int);
    size_t midOff   = (idxBytes + 255) & ~(size_t)255;
    float* mid      = (float*)((char*)d_ws + midOff);

    hipMemsetAsync(idx, 0xFF, idxBytes, stream);                       // idx = -1
    hipMemsetAsync(d_out, 0, (size_t)out_size * sizeof(float), stream); // dense zeros

    scatter_idx_kernel<<<(n + 255) / 256, 256, 0, stream>>>(coors, idx, n);

    const int NV = BATCH * MD * MH * MW;   // 249,640 mid voxels
    mid_kernel<<<(NV + 3) / 4, 256, 0, stream>>>(feat, idx, w1, mid);

    out_kernel<<<(int)(((size_t)n * 32 + 255) / 256), 256, 0, stream>>>(coors, mid, w2, out, n);
}

// Round 2
// 1020.501 us; speedup vs baseline: 1.5111x; 1.5111x over previous
//
#include <hip/hip_runtime.h>

// Problem constants (match reference)
#define D_   41
#define H_   159
#define W_   159
#define MD   20
#define MH   79
#define MW   79
#define CIN  32
#define COUT 64
#define BATCH 2

// Scatter point index into dense idx grid (-1 = empty).
__global__ void scatter_idx_kernel(const int* __restrict__ coors,
                                   int* __restrict__ idx, int n) {
    int i = blockIdx.x * blockDim.x + threadIdx.x;
    if (i >= n) return;
    int b = coors[i * 4 + 0];
    int z = coors[i * 4 + 1];
    int y = coors[i * 4 + 2];
    int x = coors[i * 4 + 3];
    idx[((b * D_ + z) * H_ + y) * W_ + x] = i;
}

// Compute mid[b,zo,yo,xo,co] densely via gather over 27 taps.
// 256 threads = 4 voxels x 64 lanes (one lane per co).
__global__ __launch_bounds__(256) void mid_kernel(const float* __restrict__ feat,
                                                  const int* __restrict__ idx,
                                                  const float* __restrict__ w1,
                                                  float* __restrict__ mid) {
    const int NV = BATCH * MD * MH * MW;
    int co = threadIdx.x & 63;
    int v  = blockIdx.x * 4 + (threadIdx.x >> 6);
    if (v >= NV) return;
    int xo = v % MW; int t = v / MW;
    int yo = t % MH; t /= MH;
    int zo = t % MD; int b = t / MD;

    int zi0 = 2 * zo, yi0 = 2 * yo, xi0 = 2 * xo;
    float acc = 0.f;
    for (int kz = 0; kz < 3; ++kz) {
        for (int ky = 0; ky < 3; ++ky) {
            const int* row = idx + ((b * D_ + zi0 + kz) * H_ + yi0 + ky) * W_ + xi0;
            #pragma unroll
            for (int kx = 0; kx < 3; ++kx) {
                int p = row[kx];                      // wave-uniform broadcast load
                if (p >= 0) {
                    const float4* f4 = (const float4*)(feat + (size_t)p * CIN);
                    const float* w = w1 + (((kz * 3 + ky) * 3 + kx) * CIN * COUT) + co;
                    #pragma unroll
                    for (int j = 0; j < CIN / 4; ++j) {
                        float4 f = f4[j];             // 16B broadcast load
                        acc = fmaf(f.x, w[(4 * j + 0) * COUT], acc);
                        acc = fmaf(f.y, w[(4 * j + 1) * COUT], acc);
                        acc = fmaf(f.z, w[(4 * j + 2) * COUT], acc);
                        acc = fmaf(f.w, w[(4 * j + 3) * COUT], acc);
                    }
                }
            }
        }
    }
    mid[(size_t)v * COUT + co] = acc;
}

// Adjoint conv at masked voxels. One WAVE per point, lane = co.
// acc[ci] per lane (partial over this lane's co), LDS transpose reduction.
__global__ __launch_bounds__(256) void out_kernel(const int* __restrict__ coors,
                                                  const float* __restrict__ mid,
                                                  const float* __restrict__ w2,
                                                  float* __restrict__ out, int n) {
    __shared__ float red[4][64 * 33];   // per-wave transpose scratch (stride 33: conflict-free)
    int lane = threadIdx.x & 63;
    int wid  = threadIdx.x >> 6;
    int i    = blockIdx.x * 4 + wid;
    if (i >= n) return;
    int b = coors[i * 4 + 0];
    int z = coors[i * 4 + 1];
    int y = coors[i * 4 + 2];
    int x = coors[i * 4 + 3];

    float acc[CIN];
    #pragma unroll
    for (int ci = 0; ci < CIN; ++ci) acc[ci] = 0.f;

    for (int kz = 0; kz < 3; ++kz) {
        int zr = z - kz;
        if (zr < 0 || (zr & 1)) continue;
        int zo = zr >> 1; if (zo >= MD) continue;
        for (int ky = 0; ky < 3; ++ky) {
            int yr = y - ky;
            if (yr < 0 || (yr & 1)) continue;
            int yo = yr >> 1; if (yo >= MH) continue;
            for (int kx = 0; kx < 3; ++kx) {
                int xr = x - kx;
                if (xr < 0 || (xr & 1)) continue;
                int xo = xr >> 1; if (xo >= MW) continue;
                int v = ((b * MD + zo) * MH + yo) * MW + xo;
                float m = mid[(size_t)v * COUT + lane];          // coalesced 256B
                const float* w = w2 + (((kz * 3 + ky) * 3 + kx) * CIN * COUT) + lane;
                #pragma unroll
                for (int ci = 0; ci < CIN; ++ci)
                    acc[ci] = fmaf(m, w[ci * COUT], acc[ci]);    // coalesced 256B per ci
            }
        }
    }

    // Cross-lane reduction: sum acc[ci] over all 64 lanes (co).
    float* r = red[wid];
    #pragma unroll
    for (int ci = 0; ci < CIN; ++ci)
        r[lane * 33 + ci] = acc[ci];         // banks (lane+ci)%32: conflict-free
    int h  = lane >> 5;
    int ci = lane & 31;
    float s = 0.f;
    #pragma unroll
    for (int j = 0; j < 32; ++j)
        s += r[(h * 32 + j) * 33 + ci];      // 2-way bank alias: free
    s += __shfl_xor(s, 32, 64);
    if (lane < 32)
        out[((size_t)(b * CIN + ci) * D_ + z) * (H_ * W_) + (size_t)y * W_ + x] = s;
}

extern "C" void kernel_launch(void* const* d_in, const int* in_sizes, int n_in,
                              void* d_out, int out_size, void* d_ws, size_t ws_size,
                              hipStream_t stream) {
    const float* feat  = (const float*)d_in[0];
    const int*   coors = (const int*)d_in[1];
    const float* w1    = (const float*)d_in[3];
    const float* w2    = (const float*)d_in[4];
    float*       out   = (float*)d_out;

    int n = in_sizes[0] / CIN;   // 150000 points total

    int*   idx      = (int*)d_ws;
    size_t idxBytes = (size_t)BATCH * D_ * H_ * W_ * sizeof(int);
    size_t midOff   = (idxBytes + 255) & ~(size_t)255;
    float* mid      = (float*)((char*)d_ws + midOff);

    hipMemsetAsync(idx, 0xFF, idxBytes, stream);                        // idx = -1
    hipMemsetAsync(d_out, 0, (size_t)out_size * sizeof(float), stream); // dense zeros

    scatter_idx_kernel<<<(n + 255) / 256, 256, 0, stream>>>(coors, idx, n);

    const int NV = BATCH * MD * MH * MW;   // 249,640 mid voxels
    mid_kernel<<<(NV + 3) / 4, 256, 0, stream>>>(feat, idx, w1, mid);

    out_kernel<<<(n + 3) / 4, 256, 0, stream>>>(coors, mid, w2, out, n);
}

// Round 3
// 782.183 us; speedup vs baseline: 1.9715x; 1.3047x over previous
//
#include <hip/hip_runtime.h>

// Problem constants (match reference)
#define D_   41
#define H_   159
#define W_   159
#define MD   20
#define MH   79
#define MW   79
#define CIN  32
#define COUT 64
#define BATCH 2

// Scatter point index into dense idx grid (-1 = empty).
__global__ void scatter_idx_kernel(const int* __restrict__ coors,
                                   int* __restrict__ idx, int n) {
    int i = blockIdx.x * blockDim.x + threadIdx.x;
    if (i >= n) return;
    int4 c = ((const int4*)coors)[i];
    idx[((c.x * D_ + c.y) * H_ + c.z) * W_ + c.w] = i;
}

// mid[b,zo,yo,xo,co] via gather. One wave per voxel, lane = co.
// All 27 taps probed lane-parallel (1 load), hits compacted via ballot.
__global__ __launch_bounds__(256) void mid_kernel(const float* __restrict__ feat,
                                                  const int* __restrict__ idx,
                                                  const float* __restrict__ w1,
                                                  float* __restrict__ mid) {
    const int NV = BATCH * MD * MH * MW;
    int lane = threadIdx.x & 63;
    int v    = blockIdx.x * 4 + (threadIdx.x >> 6);
    if (v >= NV) return;
    int xo = v % MW; int t0 = v / MW;
    int yo = t0 % MH; t0 /= MH;
    int zo = t0 % MD; int b = t0 / MD;

    // Lane-parallel probe of 27 taps (all in-bounds for VALID strided conv).
    int l  = lane < 27 ? lane : 26;
    int kz = l / 9, kr = l % 9;
    int ky = kr / 3, kx = kr % 3;
    int base = ((b * D_ + 2 * zo + kz) * H_ + 2 * yo + ky) * W_ + 2 * xo + kx;
    int p = -1;
    if (lane < 27) p = idx[base];
    unsigned long long m = __ballot(p >= 0);

    float acc = 0.f;
    while (m) {
        int t = __builtin_ctzll(m);   // tap index = lane that hit
        m &= m - 1;
        int pp = __shfl(p, t);        // broadcast point index
        const float4* f4 = (const float4*)(feat + (size_t)pp * CIN);
        const float*  w  = w1 + t * (CIN * COUT) + lane;
        #pragma unroll
        for (int j = 0; j < CIN / 4; ++j) {
            float4 f = f4[j];         // 16B broadcast load
            acc = fmaf(f.x, w[(4 * j + 0) * COUT], acc);
            acc = fmaf(f.y, w[(4 * j + 1) * COUT], acc);
            acc = fmaf(f.z, w[(4 * j + 2) * COUT], acc);
            acc = fmaf(f.w, w[(4 * j + 3) * COUT], acc);
        }
    }
    mid[(size_t)v * COUT + lane] = acc;
}

// Adjoint conv at masked voxels. One wave per point, lane = co.
// Valid taps (parity/bounds-filtered, <=8) probed lane-parallel + ballot.
__global__ __launch_bounds__(256) void out_kernel(const int* __restrict__ coors,
                                                  const float* __restrict__ mid,
                                                  const float* __restrict__ w2,
                                                  float* __restrict__ out, int n) {
    __shared__ float red[4][64 * 33];   // per-wave transpose scratch
    int lane = threadIdx.x & 63;
    int wid  = threadIdx.x >> 6;
    int i    = blockIdx.x * 4 + wid;
    if (i >= n) return;
    int4 c = ((const int4*)coors)[i];
    int b = c.x, z = c.y, y = c.z, x = c.w;

    // Lane-parallel validity probe of 27 candidate taps.
    int l  = lane < 27 ? lane : 26;
    int kz = l / 9, kr = l % 9;
    int ky = kr / 3, kx = kr % 3;
    int zr = z - kz, yr = y - ky, xr = x - kx;
    bool ok = (lane < 27) &&
              zr >= 0 && !(zr & 1) && (zr >> 1) < MD &&
              yr >= 0 && !(yr & 1) && (yr >> 1) < MH &&
              xr >= 0 && !(xr & 1) && (xr >> 1) < MW;
    int vv = ok ? ((b * MD + (zr >> 1)) * MH + (yr >> 1)) * MW + (xr >> 1) : -1;
    unsigned long long m = __ballot(ok);

    float acc[CIN];
    #pragma unroll
    for (int ci = 0; ci < CIN; ++ci) acc[ci] = 0.f;

    while (m) {
        int t = __builtin_ctzll(m);
        m &= m - 1;
        int v = __shfl(vv, t);                           // broadcast voxel
        float mr = mid[(size_t)v * COUT + lane];         // coalesced 256B
        const float* w = w2 + t * (CIN * COUT) + lane;
        #pragma unroll
        for (int ci = 0; ci < CIN; ++ci)
            acc[ci] = fmaf(mr, w[ci * COUT], acc[ci]);   // coalesced 256B per ci
    }

    // Cross-lane reduction: sum acc[ci] over all 64 lanes (co).
    float* r = red[wid];
    #pragma unroll
    for (int ci = 0; ci < CIN; ++ci)
        r[lane * 33 + ci] = acc[ci];
    int h  = lane >> 5;
    int ci = lane & 31;
    float s = 0.f;
    #pragma unroll
    for (int j = 0; j < 32; ++j)
        s += r[(h * 32 + j) * 33 + ci];
    s += __shfl_xor(s, 32, 64);
    if (lane < 32)
        out[((size_t)(b * CIN + ci) * D_ + z) * (H_ * W_) + (size_t)y * W_ + x] = s;
}

extern "C" void kernel_launch(void* const* d_in, const int* in_sizes, int n_in,
                              void* d_out, int out_size, void* d_ws, size_t ws_size,
                              hipStream_t stream) {
    const float* feat  = (const float*)d_in[0];
    const int*   coors = (const int*)d_in[1];
    const float* w1    = (const float*)d_in[3];
    const float* w2    = (const float*)d_in[4];
    float*       out   = (float*)d_out;

    int n = in_sizes[0] / CIN;   // 150000 points total

    int*   idx      = (int*)d_ws;
    size_t idxBytes = (size_t)BATCH * D_ * H_ * W_ * sizeof(int);
    size_t midOff   = (idxBytes + 255) & ~(size_t)255;
    float* mid      = (float*)((char*)d_ws + midOff);

    hipMemsetAsync(idx, 0xFF, idxBytes, stream);                        // idx = -1
    hipMemsetAsync(d_out, 0, (size_t)out_size * sizeof(float), stream); // dense zeros

    scatter_idx_kernel<<<(n + 255) / 256, 256, 0, stream>>>(coors, idx, n);

    const int NV = BATCH * MD * MH * MW;   // 249,640 mid voxels
    mid_kernel<<<(NV + 3) / 4, 256, 0, stream>>>(feat, idx, w1, mid);

    out_kernel<<<(n + 3) / 4, 256, 0, stream>>>(coors, mid, w2, out, n);
}